// Round 1
// baseline (384.210 us; speedup 1.0000x reference)
//
#include <hip/hip_runtime.h>
#include <stdint.h>

#define NN 100000      // nodes
#define NE 1600000     // edges
#define MAXDEG 64      // Poisson(16): P(deg>64) ~ 1e-19, safe cap
#define NSLICE 8       // XCD count; slice = blockIdx & 7 (perf heuristic only)
#define SLICE_SZ 12500 // nodes per slice
#define CHUNK 6400     // edges per block; NE/CHUNK = 250 chunks per slice

typedef __attribute__((ext_vector_type(8))) short short8;
typedef __attribute__((ext_vector_type(4))) float f32x4;

__device__ __forceinline__ float bflo(unsigned v) { return __uint_as_float(v << 16); }
__device__ __forceinline__ float bfhi(unsigned v) { return __uint_as_float(v & 0xffff0000u); }
__device__ __forceinline__ unsigned short f2bf(float f) {   // round-to-nearest-even
  unsigned u = __float_as_uint(f);
  u += 0x7fff + ((u >> 16) & 1);
  return (unsigned short)(u >> 16);
}

// ---- XCD-sliced bucket build: per-XCD write region 3.2MB -> L2-resident ----
__global__ __launch_bounds__(256) void build_buckets(const int* __restrict__ src,
                                                     const int* __restrict__ dst,
                                                     int* __restrict__ cnt,
                                                     int* __restrict__ buck) {
  const int slice = blockIdx.x & (NSLICE - 1);
  const int chunk = blockIdx.x >> 3;
  const int c0 = chunk * CHUNK;
  const int lo = slice * SLICE_SZ, hi = lo + SLICE_SZ;
  for (int e = c0 + (int)threadIdx.x * 4; e < c0 + CHUNK; e += 1024) {
    int4 d = *(const int4*)(dst + e);
    int4 s = *(const int4*)(src + e);
    if (d.x >= lo && d.x < hi) { int p = atomicAdd(&cnt[d.x], 1); if (p < MAXDEG) buck[d.x * MAXDEG + p] = s.x; }
    if (d.y >= lo && d.y < hi) { int p = atomicAdd(&cnt[d.y], 1); if (p < MAXDEG) buck[d.y * MAXDEG + p] = s.y; }
    if (d.z >= lo && d.z < hi) { int p = atomicAdd(&cnt[d.z], 1); if (p < MAXDEG) buck[d.z * MAXDEG + p] = s.z; }
    if (d.w >= lo && d.w < hi) { int p = atomicAdd(&cnt[d.w], 1); if (p < MAXDEG) buck[d.w * MAXDEG + p] = s.w; }
  }
}

// ---- f32 -> packed bf16x2 (float4 per thread) ----
__global__ __launch_bounds__(256) void to_bf16(const float* __restrict__ x,
                                               unsigned* __restrict__ xb) {
  int i = blockIdx.x * 256 + threadIdx.x;     // over NN*32
  if (i >= NN * 32) return;
  float4 v = ((const float4*)x)[i];
  uint2 o;
  o.x = ((unsigned)f2bf(v.y) << 16) | f2bf(v.x);
  o.y = ((unsigned)f2bf(v.w) << 16) | f2bf(v.z);
  ((uint2*)xb)[i] = o;
}

// ---- one-time W transpose -> k-major bf16: WT[m][k], k = [Wl rows | Wr rows] ----
__global__ __launch_bounds__(256) void transpose_w(const float* __restrict__ W1l,
                                                   const float* __restrict__ W1r,
                                                   const float* __restrict__ W2l,
                                                   const float* __restrict__ W2r,
                                                   unsigned short* __restrict__ WT1,
                                                   unsigned short* __restrict__ WT2) {
  int t = blockIdx.x * 256 + threadIdx.x;
  if (t < 128 * 256) {
    int m = t >> 8, k = t & 255;
    float v = (k < 128) ? W1l[k * 128 + m] : W1r[(k - 128) * 128 + m];
    WT1[t] = f2bf(v);
  } else {
    int i = t - 128 * 256;
    if (i < 64 * 256) {
      int m = i >> 8, k = i & 255;
      float v = (k < 128) ? W2l[k * 64 + m] : W2r[(k - 128) * 64 + m];
      WT2[i] = f2bf(v);
    }
  }
}

// ---- FUSED layer: gather-mean directly into LDS, then MFMA. BARRIER-FREE:
// wave wv owns sA rows [wv*16, wv*16+16) exclusively. v2 changes:
//  * split-K staging: rows hold 128 channels (agg), MFMA k[0,128), then the
//    SAME rows are overwritten with x and MFMA k[128,256) runs (acc carries).
//    LDS 33792 -> 17408 B (64 x 136 shorts, 272B pitch = 16B-aligned):
//    LDS cap 4 -> 9 blocks/CU; occupancy becomes grid-bound (~24 waves/CU).
//  * gather loads uint2 (2 edges per load instr, 32 lanes/edge): halves
//    bpermute/load/clamp issue count at identical bytes in flight; groups
//    merged with one __shfl_xor(...,32) per accumulator per node.
//  * xr loads moved out of prefetch (shorter live range), issued right
//    before MFMA half-A so latency hides under it.
template <int M, bool RELU, typename OutT>
__global__ __launch_bounds__(256) void sage_fused(const unsigned* __restrict__ xb,
                                                  const int* __restrict__ cnt,
                                                  const int* __restrict__ buck,
                                                  const unsigned short* __restrict__ WT,
                                                  const float* __restrict__ bias,
                                                  OutT* __restrict__ out) {
  __shared__ unsigned short sA[64][136];         // 272B pitch; 17408 B total

  const int t = threadIdx.x;
  const int lane = t & 63;
  const int wv = t >> 6;
  const int node0 = blockIdx.x * 64;
  const int nb = node0 + wv * 16;                // this wave's 16 nodes
  const int g = lane >> 5;                       // edge subset (0/1)
  const int c = lane & 31;                       // channel quad: ch [4c, 4c+4)

  // ---- prefetch: 16 bucket rows + 16 degrees (independent loads) ----
  int slot[16]; int deg[16];
#pragma unroll
  for (int i = 0; i < 16; i++) {
    int node = nb + i;
    if (node < NN) {                             // lane-uniform branch
      slot[i] = buck[(size_t)node * MAXDEG + lane];
      deg[i]  = cnt[node];
    } else { slot[i] = 0; deg[i] = 0; }
  }

  // ---- gather-mean each of my 16 rows into wave-private LDS (agg half) ----
#pragma unroll
  for (int i = 0; i < 16; i++) {
    float a0 = 0.f, a1 = 0.f, a2 = 0.f, a3 = 0.f;
    int d = deg[i] < MAXDEG ? deg[i] : MAXDEG;
    if (d > 0) {                                 // wave-uniform
      int last = d - 1;
      for (int p = 0; p < d; p += 16) {          // 16 edges per chunk, 8 loads
        uint2 v[8];
#pragma unroll
        for (int j = 0; j < 8; j++) {
          int e = p + 2 * j + g;
          int s = __shfl(slot[i], e < last ? e : last, 64);
          v[j] = *(const uint2*)(xb + (size_t)s * 64 + c * 2);  // 8B/lane, 512B/edge-pair
        }
#pragma unroll
        for (int j = 0; j < 8; j++) {
          int e = p + 2 * j + g;
          unsigned w0 = (e <= last) ? v[j].x : 0u;
          unsigned w1 = (e <= last) ? v[j].y : 0u;
          a0 += bflo(w0); a1 += bfhi(w0);
          a2 += bflo(w1); a3 += bfhi(w1);
        }
      }
      // merge the two edge subsets (same channels live in lane l and l^32)
      a0 += __shfl_xor(a0, 32, 64);
      a1 += __shfl_xor(a1, 32, 64);
      a2 += __shfl_xor(a2, 32, 64);
      a3 += __shfl_xor(a3, 32, 64);
    }
    float inv = 1.f / (float)(deg[i] > 1 ? deg[i] : 1);   // full deg (uncapped), as before
    unsigned pk0 = ((unsigned)f2bf(a1 * inv) << 16) | f2bf(a0 * inv);
    unsigned pk1 = ((unsigned)f2bf(a3 * inv) << 16) | f2bf(a2 * inv);
    if (g == 0) {                                // both halves hold identical sums
      uint2 o; o.x = pk0; o.y = pk1;
      *(uint2*)((unsigned*)&sA[wv * 16 + i][0] + 2 * c) = o;
    }
  }

  // ---- MFMA: A from my LDS rows, B from k-major WT in global (L2-hot) ----
  const int m = lane & 15;
  const int q = lane >> 4;

  f32x4 acc[M / 16];
#pragma unroll
  for (int cc = 0; cc < M / 16; cc++) acc[cc] = {0.f, 0.f, 0.f, 0.f};

  // issue x-row loads now; latency hides under MFMA half-A
  unsigned xr[16];
#pragma unroll
  for (int i = 0; i < 16; i++) {
    int node = nb + i;
    xr[i] = (node < NN) ? xb[(size_t)node * 64 + lane] : 0u;
  }

  // half A: k in [0,128) -> agg @ Wl-rows
#pragma unroll
  for (int ks = 0; ks < 4; ks++) {
    short8 a = *(const short8*)&sA[wv * 16 + m][ks * 32 + q * 8];
#pragma unroll
    for (int cc = 0; cc < M / 16; cc++) {
      short8 b = *(const short8*)(WT + (size_t)(cc * 16 + m) * 256 + ks * 32 + q * 8);
      acc[cc] = __builtin_amdgcn_mfma_f32_16x16x32_bf16(a, b, acc[cc], 0, 0, 0);
    }
  }

  // overwrite my rows with x (per-wave LDS ordering makes read->write safe)
#pragma unroll
  for (int i = 0; i < 16; i++)
    ((unsigned*)&sA[wv * 16 + i][0])[lane] = xr[i];

  // half B: k in [128,256) -> x @ Wr-rows (accumulator carries)
#pragma unroll
  for (int ks = 4; ks < 8; ks++) {
    short8 a = *(const short8*)&sA[wv * 16 + m][(ks - 4) * 32 + q * 8];
#pragma unroll
    for (int cc = 0; cc < M / 16; cc++) {
      short8 b = *(const short8*)(WT + (size_t)(cc * 16 + m) * 256 + ks * 32 + q * 8);
      acc[cc] = __builtin_amdgcn_mfma_f32_16x16x32_bf16(a, b, acc[cc], 0, 0, 0);
    }
  }

  // ---- epilogue: restage C through my (dead) sA rows -> full-line stores ----
#pragma unroll
  for (int cc = 0; cc < M / 16; cc++) {
    int col = cc * 16 + m;
    float bc = bias[col];
#pragma unroll
    for (int r = 0; r < 4; r++) {
      int lr = wv * 16 + q * 4 + r;               // D[row=q*4+r][col=m]
      float v = acc[cc][r] + bc;
      if (RELU) v = fmaxf(v, 0.f);
      if constexpr (sizeof(OutT) == 2) sA[lr][col] = f2bf(v);
      else ((float*)&sA[lr][0])[col] = v;
    }
  }
#pragma unroll
  for (int it = 0; it < 4; it++) {
    int idx = it * 64 + lane;                     // 16 rows x 16 chunks of 16B
    int rr = idx >> 4, ck = idx & 15;
    int node = node0 + wv * 16 + rr;
    if (node < NN) {
      uint4 v = *(const uint4*)((const char*)&sA[wv * 16 + rr][0] + ck * 16);
      *(uint4*)((char*)(out + (size_t)node * M) + ck * 16) = v;
    }
  }
}

extern "C" void kernel_launch(void* const* d_in, const int* in_sizes, int n_in,
                              void* d_out, int out_size, void* d_ws, size_t ws_size,
                              hipStream_t stream) {
  const float* x   = (const float*)d_in[0];
  const int*   ei  = (const int*)d_in[1];
  const float* W1l = (const float*)d_in[2];
  const float* b1  = (const float*)d_in[3];
  const float* W1r = (const float*)d_in[4];
  const float* W2l = (const float*)d_in[5];
  const float* b2  = (const float*)d_in[6];
  const float* W2r = (const float*)d_in[7];
  float* out = (float*)d_out;

  // ws: cnt 0.5MB | buck 25.6MB | xbf 12.8MB | h 12.8MB | WT1 | WT2
  char* ws = (char*)d_ws;
  int* cnt  = (int*)ws;                                   ws += (512 << 10);
  int* buck = (int*)ws;                                   ws += (size_t)NN * MAXDEG * 4;
  unsigned* xbf = (unsigned*)ws;                          ws += (size_t)NN * 64 * 4;
  unsigned* hb = (unsigned*)ws;                           ws += (size_t)NN * 64 * 4;
  unsigned short* WT1 = (unsigned short*)ws;              ws += 128 * 256 * 2;
  unsigned short* WT2 = (unsigned short*)ws;              ws += 64 * 256 * 2;

  const int* src = ei;        // edge_index[0]
  const int* dst = ei + NE;   // edge_index[1]

  hipMemsetAsync(cnt, 0, (size_t)NN * 4, stream);
  build_buckets<<<NSLICE * (NE / CHUNK), 256, 0, stream>>>(src, dst, cnt, buck);
  to_bf16<<<(NN * 32 + 255) / 256, 256, 0, stream>>>(x, xbf);
  transpose_w<<<192, 256, 0, stream>>>(W1l, W1r, W2l, W2r, WT1, WT2);

  // layer 1: h = relu([mean|x] @ [W1l;W1r] + b1), bf16
  sage_fused<128, true, unsigned short><<<(NN + 63) / 64, 256, 0, stream>>>(
      xbf, cnt, buck, WT1, b1, (unsigned short*)hb);

  // layer 2: out = [mean|h] @ [W2l;W2r] + b2, f32
  sage_fused<64, false, float><<<(NN + 63) / 64, 256, 0, stream>>>(
      hb, cnt, buck, WT2, b2, out);
}